// Round 1
// baseline (466.824 us; speedup 1.0000x reference)
//
#include <hip/hip_runtime.h>
#include <hip/hip_bf16.h>
#include <stdint.h>

typedef __attribute__((ext_vector_type(8))) short short8;
typedef __attribute__((ext_vector_type(8))) uint16_t ushort8;
typedef __attribute__((ext_vector_type(4))) float floatx4;

#define TM 128
#define TN 128
#define TK 32

// ---------- helpers ----------

__device__ __forceinline__ uint16_t f2bf_bits(float f) {
    // round-to-nearest-even fp32 -> bf16 (inputs are finite; no NaN path needed)
    uint32_t u = __builtin_bit_cast(uint32_t, f);
    u += 0x7FFFu + ((u >> 16) & 1u);
    return (uint16_t)(u >> 16);
}

__device__ __forceinline__ void async_copy16(const void* g, void* l) {
    // global -> LDS direct copy, 16B per lane. LDS dest is wave-uniform base
    // + lane*16 (m104/m108), so `l` must be wave-uniform.
    auto gp = (const __attribute__((address_space(1))) uint32_t*)(uintptr_t)g;
    auto lp = (__attribute__((address_space(3))) uint32_t*)(uint32_t)(uintptr_t)l;
    __builtin_amdgcn_global_load_lds(gp, lp, 16, 0, 0);
}

// ---------- fp32 -> bf16 conversion kernels ----------

__global__ void cvt8(const float* __restrict__ src, uint16_t* __restrict__ dst, int n) {
    int i = (blockIdx.x * 256 + threadIdx.x) * 8;
    if (i >= n) return;
    floatx4 a = *(const floatx4*)(src + i);
    floatx4 b = *(const floatx4*)(src + i + 4);
    ushort8 o;
#pragma unroll
    for (int k = 0; k < 4; k++) {
        o[k]     = f2bf_bits(a[k]);
        o[k + 4] = f2bf_bits(b[k]);
    }
    *(ushort8*)(dst + i) = o;
}

// W2 [51][2048] fp32 -> [128][2048] bf16, rows >= 51 zeroed (ws is poisoned 0xAA)
__global__ void cvt_pad_w2(const float* __restrict__ src, uint16_t* __restrict__ dst) {
    int i = (blockIdx.x * 256 + threadIdx.x) * 8;   // over 128*2048
    int row = i >> 11;
    ushort8 o;
    if (row < 51) {
        floatx4 a = *(const floatx4*)(src + i);
        floatx4 b = *(const floatx4*)(src + i + 4);
#pragma unroll
        for (int k = 0; k < 4; k++) {
            o[k]     = f2bf_bits(a[k]);
            o[k + 4] = f2bf_bits(b[k]);
        }
    } else {
#pragma unroll
        for (int k = 0; k < 8; k++) o[k] = 0;
    }
    *(ushort8*)(dst + i) = o;
}

// ---------- GEMM: C[m,n] = act( sum_k A[m,k]*W[n,k] + bias[n] ) ----------
// A [M,K] bf16 row-major, W [N,K] bf16 row-major (PyTorch layout = B^T GEMM).
// 128x128 tile, 4 waves each owning a 64x64 quadrant as 4x4 of 16x16x32 MFMAs.

template <bool RELU, bool OUTF32>
__global__ __launch_bounds__(256)
void gemm_bt(const uint16_t* __restrict__ A,
             const uint16_t* __restrict__ W,
             const float* __restrict__ bias,
             void* __restrict__ out,
             int M, int N, int K, int ldc, int nstore)
{
    __shared__ alignas(16) uint16_t sA[TM * TK];   // 8 KB
    __shared__ alignas(16) uint16_t sB[TN * TK];   // 8 KB

    const int tid  = threadIdx.x;
    const int wave = tid >> 6;
    const int lane = tid & 63;
    const int m0 = blockIdx.x * TM;
    const int n0 = blockIdx.y * TN;

    floatx4 acc[4][4];
    const floatx4 zero = {0.f, 0.f, 0.f, 0.f};
#pragma unroll
    for (int i = 0; i < 4; i++)
#pragma unroll
        for (int j = 0; j < 4; j++) acc[i][j] = zero;

    const int wr = (wave >> 1) * 64;   // wave quadrant row offset in tile
    const int wc = (wave & 1) * 64;    // wave quadrant col offset

    // staging: each lane copies 16B; chunk c = j*4+wave covers rows [c*16, c*16+16)
    const int srow = lane >> 2;          // 0..15 within chunk
    const int scol = (lane & 3) * 8;     // 0,8,16,24 (bf16 elems)

    // fragment addressing (A-layout: A[m=lane&15][k=(lane>>4)*8 + j])
    const int fm = lane & 15;
    const int fk = (lane >> 4) * 8;

    for (int k0 = 0; k0 < K; k0 += TK) {
#pragma unroll
        for (int j = 0; j < 2; j++) {
            const int c = j * 4 + wave;
            const size_t arow = (size_t)(m0 + c * 16 + srow) * K + k0 + scol;
            const size_t brow = (size_t)(n0 + c * 16 + srow) * K + k0 + scol;
            async_copy16(A + arow, sA + c * 16 * TK);   // lds dest wave-uniform
            async_copy16(W + brow, sB + c * 16 * TK);
        }
        __syncthreads();   // compiler inserts s_waitcnt vmcnt(0) before barrier

        short8 af[4], bfr[4];
#pragma unroll
        for (int i = 0; i < 4; i++) {
            af[i]  = *(const short8*)(sA + (wr + i * 16 + fm) * TK + fk);
            bfr[i] = *(const short8*)(sB + (wc + i * 16 + fm) * TK + fk);
        }
#pragma unroll
        for (int i = 0; i < 4; i++)
#pragma unroll
            for (int j = 0; j < 4; j++)
                acc[i][j] = __builtin_amdgcn_mfma_f32_16x16x32_bf16(af[i], bfr[j], acc[i][j], 0, 0, 0);
        __syncthreads();
    }

    // epilogue: C/D layout col = lane&15, row = (lane>>4)*4 + reg (m89/m91)
    const int cr = (lane >> 4) * 4;
    const int cc = lane & 15;
#pragma unroll
    for (int i = 0; i < 4; i++) {
        const int gmb = m0 + wr + i * 16 + cr;
#pragma unroll
        for (int j = 0; j < 4; j++) {
            const int gn = n0 + wc + j * 16 + cc;
            if (gn < nstore) {
                const float bv = bias[gn];
#pragma unroll
                for (int r = 0; r < 4; r++) {
                    float v = acc[i][j][r] + bv;
                    if (RELU) v = fmaxf(v, 0.f);
                    const size_t idx = (size_t)(gmb + r) * ldc + gn;
                    if (OUTF32) ((float*)out)[idx] = v;
                    else        ((uint16_t*)out)[idx] = f2bf_bits(v);
                }
            }
        }
    }
}

// ---------- launch ----------

extern "C" void kernel_launch(void* const* d_in, const int* in_sizes, int n_in,
                              void* d_out, int out_size, void* d_ws, size_t ws_size,
                              hipStream_t stream) {
    (void)in_sizes; (void)n_in; (void)out_size; (void)ws_size;
    // inputs: 0 num_pairs, 1 classifier_input, 2 num_batches,
    //         3 W0[2048,1024], 4 b0, 5 W1[2048,2048], 6 b1, 7 W2[51,2048], 8 b2
    const float* X  = (const float*)d_in[1];
    const float* W0 = (const float*)d_in[3];
    const float* b0 = (const float*)d_in[4];
    const float* W1 = (const float*)d_in[5];
    const float* b1 = (const float*)d_in[6];
    const float* W2 = (const float*)d_in[7];
    const float* b2 = (const float*)d_in[8];

    const int M = 16384;     // 16 batches * 1024 pairs

    char* w = (char*)d_ws;
    uint16_t* X0  = (uint16_t*)w; w += (size_t)M * 1024 * 2;      // 33.5 MB
    uint16_t* X1  = (uint16_t*)w; w += (size_t)M * 2048 * 2;      // 67 MB
    uint16_t* X2  = (uint16_t*)w; w += (size_t)M * 2048 * 2;      // 67 MB
    uint16_t* W0b = (uint16_t*)w; w += (size_t)2048 * 1024 * 2;   // 4.2 MB
    uint16_t* W1b = (uint16_t*)w; w += (size_t)2048 * 2048 * 2;   // 8.4 MB
    uint16_t* W2b = (uint16_t*)w; w += (size_t)128 * 2048 * 2;    // 0.5 MB

    // fp32 -> bf16 conversions (independent; stream-ordered before GEMMs)
    cvt8<<<M * 1024 / 8 / 256, 256, 0, stream>>>(X, X0, M * 1024);
    cvt8<<<2048 * 1024 / 8 / 256, 256, 0, stream>>>(W0, W0b, 2048 * 1024);
    cvt8<<<2048 * 2048 / 8 / 256, 256, 0, stream>>>(W1, W1b, 2048 * 2048);
    cvt_pad_w2<<<128 * 2048 / 8 / 256, 256, 0, stream>>>(W2, W2b);

    // layer 0: [16384,1024] x [2048,1024]^T -> relu -> bf16 [16384,2048]
    gemm_bt<true, false><<<dim3(M / TM, 2048 / TN), 256, 0, stream>>>(
        X0, W0b, b0, X1, M, 2048, 1024, 2048, 2048);
    // layer 1: [16384,2048] x [2048,2048]^T -> relu -> bf16 [16384,2048]
    gemm_bt<true, false><<<dim3(M / TM, 2048 / TN), 256, 0, stream>>>(
        X1, W1b, b1, X2, M, 2048, 2048, 2048, 2048);
    // layer 2: [16384,2048] x [128(pad 51),2048]^T -> fp32 out, cols < 51
    gemm_bt<false, true><<<dim3(M / TM, 1), 256, 0, stream>>>(
        X2, W2b, b2, d_out, M, 128, 2048, 51, 51);
}

// Round 2
// 419.663 us; speedup vs baseline: 1.1124x; 1.1124x over previous
//
#include <hip/hip_runtime.h>
#include <hip/hip_bf16.h>
#include <stdint.h>

typedef __attribute__((ext_vector_type(8))) short short8;
typedef __attribute__((ext_vector_type(8))) uint16_t ushort8;
typedef __attribute__((ext_vector_type(4))) float floatx4;

#define TK 32

// ---------- helpers ----------

__device__ __forceinline__ uint16_t f2bf_bits(float f) {
    uint32_t u = __builtin_bit_cast(uint32_t, f);
    u += 0x7FFFu + ((u >> 16) & 1u);
    return (uint16_t)(u >> 16);
}

__device__ __forceinline__ void async_copy16(const void* g, void* l) {
    // global -> LDS direct copy, 16B/lane; LDS dest = wave-uniform base + lane*16
    auto gp = (const __attribute__((address_space(1))) uint32_t*)(uintptr_t)g;
    auto lp = (__attribute__((address_space(3))) uint32_t*)(uint32_t)(uintptr_t)l;
    __builtin_amdgcn_global_load_lds(gp, lp, 16, 0, 0);
}

// ---------- fp32 -> bf16 conversion kernels ----------

__global__ void cvt8(const float* __restrict__ src, uint16_t* __restrict__ dst, int n) {
    int i = (blockIdx.x * 256 + threadIdx.x) * 8;
    if (i >= n) return;
    floatx4 a = *(const floatx4*)(src + i);
    floatx4 b = *(const floatx4*)(src + i + 4);
    ushort8 o;
#pragma unroll
    for (int k = 0; k < 4; k++) {
        o[k]     = f2bf_bits(a[k]);
        o[k + 4] = f2bf_bits(b[k]);
    }
    *(ushort8*)(dst + i) = o;
}

// W2 [51][2048] fp32 -> [128][2048] bf16, rows >= 51 zeroed
__global__ void cvt_pad_w2(const float* __restrict__ src, uint16_t* __restrict__ dst) {
    int i = (blockIdx.x * 256 + threadIdx.x) * 8;   // over 128*2048
    int row = i >> 11;
    ushort8 o;
    if (row < 51) {
        floatx4 a = *(const floatx4*)(src + i);
        floatx4 b = *(const floatx4*)(src + i + 4);
#pragma unroll
        for (int k = 0; k < 4; k++) {
            o[k]     = f2bf_bits(a[k]);
            o[k + 4] = f2bf_bits(b[k]);
        }
    } else {
#pragma unroll
        for (int k = 0; k < 8; k++) o[k] = 0;
    }
    *(ushort8*)(dst + i) = o;
}

// ---------- GEMM: C[m,n] = act( sum_k A[m,k]*W[n,k] + bias[n] ) ----------
// A [M,K] bf16 row-major, W [N,K] bf16 row-major (PyTorch layout = B^T GEMM).
// Block = 256 threads = 4 waves in 2x2; wave tile = (MI*16) x (NJ*16).
// Block tile = (MI*32) x (NJ*32).  TK=32, single-buffered LDS,
// global_load_lds width-16 staging.

template <int MI, int NJ, bool RELU, bool OUTF32>
__global__ __launch_bounds__(256, 2)
void gemm_bt(const uint16_t* __restrict__ A,
             const uint16_t* __restrict__ W,
             const float* __restrict__ bias,
             void* __restrict__ out,
             int M, int N, int K, int ldc, int nstore)
{
    constexpr int TMv = MI * 32;          // block tile rows
    constexpr int TNv = NJ * 32;          // block tile cols
    constexpr int ACH = MI / 2;           // A 1KB-chunks per wave (TMv/16/4)
    constexpr int NCH = NJ / 2;           // B 1KB-chunks per wave

    __shared__ alignas(16) uint16_t sA[TMv * TK];
    __shared__ alignas(16) uint16_t sB[TNv * TK];

    const int tid  = threadIdx.x;
    const int wave = tid >> 6;
    const int lane = tid & 63;
    const int n0 = blockIdx.x * TNv;      // n-major dispatch: consecutive blocks
    const int m0 = blockIdx.y * TMv;      // share the A tile, stream W (L2-resident)

    floatx4 acc[MI][NJ];
    const floatx4 zero = {0.f, 0.f, 0.f, 0.f};
#pragma unroll
    for (int i = 0; i < MI; i++)
#pragma unroll
        for (int j = 0; j < NJ; j++) acc[i][j] = zero;

    const int wr = (wave >> 1) * MI * 16;   // wave quadrant row offset
    const int wc = (wave & 1) * NJ * 16;    // wave quadrant col offset

    // staging: chunk = 16 rows x 64 B; lane covers (row lane>>2, col (lane&3)*8)
    const int lr = lane >> 2;
    const int lc = (lane & 3) * 8;

    // incremental per-chunk global pointers (advance by TK elems per iter)
    const uint16_t* ap[ACH];
    const uint16_t* bp[NCH];
#pragma unroll
    for (int t = 0; t < ACH; t++)
        ap[t] = A + (size_t)(m0 + (wave + 4 * t) * 16 + lr) * K + lc;
#pragma unroll
    for (int t = 0; t < NCH; t++)
        bp[t] = W + (size_t)(n0 + (wave + 4 * t) * 16 + lr) * K + lc;

    // fragment addressing (A-layout: A[m=lane&15][k=(lane>>4)*8 + j])
    const int fm = lane & 15;
    const int fk = (lane >> 4) * 8;

    const int niter = K / TK;
    for (int it = 0; it < niter; it++) {
#pragma unroll
        for (int t = 0; t < ACH; t++) {
            async_copy16(ap[t], sA + (wave + 4 * t) * 512);
            ap[t] += TK;
        }
#pragma unroll
        for (int t = 0; t < NCH; t++) {
            async_copy16(bp[t], sB + (wave + 4 * t) * 512);
            bp[t] += TK;
        }
        __syncthreads();

        short8 af[MI], bfr[NJ];
#pragma unroll
        for (int i = 0; i < MI; i++)
            af[i] = *(const short8*)(sA + (wr + i * 16 + fm) * TK + fk);
#pragma unroll
        for (int j = 0; j < NJ; j++)
            bfr[j] = *(const short8*)(sB + (wc + j * 16 + fm) * TK + fk);
#pragma unroll
        for (int i = 0; i < MI; i++)
#pragma unroll
            for (int j = 0; j < NJ; j++)
                acc[i][j] = __builtin_amdgcn_mfma_f32_16x16x32_bf16(af[i], bfr[j], acc[i][j], 0, 0, 0);
        __syncthreads();
    }

    // epilogue: C/D layout col = lane&15, row = (lane>>4)*4 + reg (m89/m91)
    const int cr = (lane >> 4) * 4;
    const int cc = lane & 15;
#pragma unroll
    for (int i = 0; i < MI; i++) {
        const int gmb = m0 + wr + i * 16 + cr;
#pragma unroll
        for (int j = 0; j < NJ; j++) {
            const int gn = n0 + wc + j * 16 + cc;
            if (gn < nstore) {
                const float bv = bias[gn];
#pragma unroll
                for (int r = 0; r < 4; r++) {
                    float v = acc[i][j][r] + bv;
                    if (RELU) v = fmaxf(v, 0.f);
                    const size_t idx = (size_t)(gmb + r) * ldc + gn;
                    if (OUTF32) ((float*)out)[idx] = v;
                    else        ((uint16_t*)out)[idx] = f2bf_bits(v);
                }
            }
        }
    }
}

// ---------- launch ----------

extern "C" void kernel_launch(void* const* d_in, const int* in_sizes, int n_in,
                              void* d_out, int out_size, void* d_ws, size_t ws_size,
                              hipStream_t stream) {
    (void)in_sizes; (void)n_in; (void)out_size; (void)ws_size;
    const float* X  = (const float*)d_in[1];
    const float* W0 = (const float*)d_in[3];
    const float* b0 = (const float*)d_in[4];
    const float* W1 = (const float*)d_in[5];
    const float* b1 = (const float*)d_in[6];
    const float* W2 = (const float*)d_in[7];
    const float* b2 = (const float*)d_in[8];

    const int M = 16384;     // 16 batches * 1024 pairs

    char* w = (char*)d_ws;
    uint16_t* X0  = (uint16_t*)w; w += (size_t)M * 1024 * 2;
    uint16_t* X1  = (uint16_t*)w; w += (size_t)M * 2048 * 2;
    uint16_t* X2  = (uint16_t*)w; w += (size_t)M * 2048 * 2;
    uint16_t* W0b = (uint16_t*)w; w += (size_t)2048 * 1024 * 2;
    uint16_t* W1b = (uint16_t*)w; w += (size_t)2048 * 2048 * 2;
    uint16_t* W2b = (uint16_t*)w; w += (size_t)128 * 2048 * 2;

    cvt8<<<M * 1024 / 8 / 256, 256, 0, stream>>>(X, X0, M * 1024);
    cvt8<<<2048 * 1024 / 8 / 256, 256, 0, stream>>>(W0, W0b, 2048 * 1024);
    cvt8<<<2048 * 2048 / 8 / 256, 256, 0, stream>>>(W1, W1b, 2048 * 2048);
    cvt_pad_w2<<<128 * 2048 / 8 / 256, 256, 0, stream>>>(W2, W2b);

    // layer 0: [16384,1024] x [2048,1024]^T -> relu -> bf16; 128x256 tiles
    gemm_bt<4, 8, true, false><<<dim3(2048 / 256, M / 128), 256, 0, stream>>>(
        X0, W0b, b0, X1, M, 2048, 1024, 2048, 2048);
    // layer 1: [16384,2048] x [2048,2048]^T -> relu -> bf16; 128x256 tiles
    gemm_bt<4, 8, true, false><<<dim3(2048 / 256, M / 128), 256, 0, stream>>>(
        X1, W1b, b1, X2, M, 2048, 2048, 2048, 2048);
    // layer 2: [16384,2048] x [128(pad 51),2048]^T -> fp32; 64x128 tiles, 256 blocks
    gemm_bt<2, 4, false, true><<<dim3(1, M / 64), 256, 0, stream>>>(
        X2, W2b, b2, d_out, M, 128, 2048, 51, 51);
}

// Round 3
// 347.569 us; speedup vs baseline: 1.3431x; 1.2074x over previous
//
#include <hip/hip_runtime.h>
#include <hip/hip_bf16.h>
#include <stdint.h>

typedef __attribute__((ext_vector_type(8))) short short8;
typedef __attribute__((ext_vector_type(8))) uint16_t ushort8;
typedef __attribute__((ext_vector_type(4))) float floatx4;

#define TK 64   // K elems staged per barrier pair

// ---------- helpers ----------

__device__ __forceinline__ uint16_t f2bf_bits(float f) {
    uint32_t u = __builtin_bit_cast(uint32_t, f);
    u += 0x7FFFu + ((u >> 16) & 1u);
    return (uint16_t)(u >> 16);
}

__device__ __forceinline__ void async_copy16(const void* g, void* l) {
    // global -> LDS direct copy, 16B/lane; LDS dest = wave-uniform base + lane*16
    auto gp = (const __attribute__((address_space(1))) uint32_t*)(uintptr_t)g;
    auto lp = (__attribute__((address_space(3))) uint32_t*)(uint32_t)(uintptr_t)l;
    __builtin_amdgcn_global_load_lds(gp, lp, 16, 0, 0);
}

// ---------- fp32 -> bf16 conversion kernels ----------

__global__ void cvt8(const float* __restrict__ src, uint16_t* __restrict__ dst, int n) {
    int i = (blockIdx.x * 256 + threadIdx.x) * 8;
    if (i >= n) return;
    floatx4 a = *(const floatx4*)(src + i);
    floatx4 b = *(const floatx4*)(src + i + 4);
    ushort8 o;
#pragma unroll
    for (int k = 0; k < 4; k++) {
        o[k]     = f2bf_bits(a[k]);
        o[k + 4] = f2bf_bits(b[k]);
    }
    *(ushort8*)(dst + i) = o;
}

// W2 [51][2048] fp32 -> [64][2048] bf16, rows >= 51 zeroed
__global__ void cvt_pad_w2(const float* __restrict__ src, uint16_t* __restrict__ dst) {
    int i = (blockIdx.x * 256 + threadIdx.x) * 8;   // over 64*2048
    int row = i >> 11;
    ushort8 o;
    if (row < 51) {
        floatx4 a = *(const floatx4*)(src + i);
        floatx4 b = *(const floatx4*)(src + i + 4);
#pragma unroll
        for (int k = 0; k < 4; k++) {
            o[k]     = f2bf_bits(a[k]);
            o[k + 4] = f2bf_bits(b[k]);
        }
    } else {
#pragma unroll
        for (int k = 0; k < 8; k++) o[k] = 0;
    }
    *(ushort8*)(dst + i) = o;
}

// ---------- GEMM: C[m,n] = act( sum_k A[m,k]*W[n,k] + bias[n] ) ----------
// A [M,K] bf16 row-major, W [N,K] bf16 row-major. 4 waves in 2x2;
// block tile = (MI*32) x (NJ*32); TK=64; global_load_lds width-16 staging.
// LDS layout: 1KB chunks of 8 rows x 8 segs(16B); seg slot s holds global
// col-group s ^ (row&7)  -> fragment ds_read_b128 spreads over all 32 banks.
// Grid is flat 1D; XCD swizzle: xcd=f&7 owns a contiguous m-super-slab,
// n-fast inner order so A-tile sharers land on the same XCD's L2.

template <int MI, int NJ, bool RELU, bool OUTF32>
__global__ __launch_bounds__(256, 2)
void gemm_bt(const uint16_t* __restrict__ A,
             const uint16_t* __restrict__ W,
             const float* __restrict__ bias,
             void* __restrict__ out,
             int M, int N, int K, int ldc, int nstore)
{
    constexpr int TMv = MI * 32;
    constexpr int TNv = NJ * 32;
    constexpr int ACH = TMv / 32;     // A 1KB-chunks per wave
    constexpr int BCH = TNv / 32;     // B 1KB-chunks per wave

    __shared__ alignas(16) uint16_t sA[TMv * TK];
    __shared__ alignas(16) uint16_t sB[TNv * TK];

    const int tid  = threadIdx.x;
    const int wave = tid >> 6;
    const int lane = tid & 63;

    // XCD-aware tile assignment
    const int f   = blockIdx.x;
    const int xcd = f & 7;
    const int loc = f >> 3;
    const int per = (int)gridDim.x >> 3;     // tiles per XCD
    const int nt  = N / TNv;                 // n tiles
    const int n_t = loc % nt;
    const int m_t = xcd * (per / nt) + loc / nt;
    const int n0 = n_t * TNv;
    const int m0 = m_t * TMv;

    floatx4 acc[MI][NJ];
    const floatx4 zero = {0.f, 0.f, 0.f, 0.f};
#pragma unroll
    for (int i = 0; i < MI; i++)
#pragma unroll
        for (int j = 0; j < NJ; j++) acc[i][j] = zero;

    const int wr = (wave >> 1) * MI * 16;   // wave quadrant row offset
    const int wc = (wave & 1) * NJ * 16;    // wave quadrant col offset

    // staging: chunk = 8 rows x 128B; lane -> row lane>>3, seg (lane&7)^row
    const int sr   = lane >> 3;
    const int scol = ((lane & 7) ^ sr) * 8;   // permuted global col-group

    const uint16_t* ap[ACH];
    const uint16_t* bp[BCH];
#pragma unroll
    for (int t = 0; t < ACH; t++)
        ap[t] = A + (size_t)(m0 + (wave + 4 * t) * 8 + sr) * K + scol;
#pragma unroll
    for (int t = 0; t < BCH; t++)
        bp[t] = W + (size_t)(n0 + (wave + 4 * t) * 8 + sr) * K + scol;

    // fragment addressing: row fm = lane&15, k-group base lane>>4
    const int fm = lane & 15;
    const int fr = fm & 7;                    // row parity for slot unswizzle
    const int kgb = lane >> 4;                // 0..3

    const int niter = K / TK;
    for (int it = 0; it < niter; it++) {
#pragma unroll
        for (int t = 0; t < ACH; t++) {
            async_copy16(ap[t], sA + (wave + 4 * t) * 512);
            ap[t] += TK;
        }
#pragma unroll
        for (int t = 0; t < BCH; t++) {
            async_copy16(bp[t], sB + (wave + 4 * t) * 512);
            bp[t] += TK;
        }
        __syncthreads();

#pragma unroll
        for (int kk = 0; kk < 2; kk++) {
            const int slot = ((kgb + 4 * kk) ^ fr) * 8;
            short8 af[MI], bfr[NJ];
#pragma unroll
            for (int i = 0; i < MI; i++)
                af[i] = *(const short8*)(sA + (wr + i * 16 + fm) * TK + slot);
#pragma unroll
            for (int j = 0; j < NJ; j++)
                bfr[j] = *(const short8*)(sB + (wc + j * 16 + fm) * TK + slot);
#pragma unroll
            for (int i = 0; i < MI; i++)
#pragma unroll
                for (int j = 0; j < NJ; j++)
                    acc[i][j] = __builtin_amdgcn_mfma_f32_16x16x32_bf16(af[i], bfr[j], acc[i][j], 0, 0, 0);
        }
        __syncthreads();
    }

    // epilogue: C/D layout col = lane&15, row = (lane>>4)*4 + reg
    const int cr = (lane >> 4) * 4;
    const int cc = lane & 15;
#pragma unroll
    for (int i = 0; i < MI; i++) {
        const int gmb = m0 + wr + i * 16 + cr;
#pragma unroll
        for (int j = 0; j < NJ; j++) {
            const int gn = n0 + wc + j * 16 + cc;
            if (gn < nstore) {
                const float bv = bias[gn];
#pragma unroll
                for (int r = 0; r < 4; r++) {
                    float v = acc[i][j][r] + bv;
                    if (RELU) v = fmaxf(v, 0.f);
                    const size_t idx = (size_t)(gmb + r) * ldc + gn;
                    if (OUTF32) ((float*)out)[idx] = v;
                    else        ((uint16_t*)out)[idx] = f2bf_bits(v);
                }
            }
        }
    }
}

// ---------- launch ----------

extern "C" void kernel_launch(void* const* d_in, const int* in_sizes, int n_in,
                              void* d_out, int out_size, void* d_ws, size_t ws_size,
                              hipStream_t stream) {
    (void)in_sizes; (void)n_in; (void)out_size; (void)ws_size;
    const float* X  = (const float*)d_in[1];
    const float* W0 = (const float*)d_in[3];
    const float* b0 = (const float*)d_in[4];
    const float* W1 = (const float*)d_in[5];
    const float* b1 = (const float*)d_in[6];
    const float* W2 = (const float*)d_in[7];
    const float* b2 = (const float*)d_in[8];

    const int M = 16384;     // 16 batches * 1024 pairs

    char* w = (char*)d_ws;
    uint16_t* X0  = (uint16_t*)w; w += (size_t)M * 1024 * 2;
    uint16_t* X1  = (uint16_t*)w; w += (size_t)M * 2048 * 2;
    uint16_t* X2  = (uint16_t*)w; w += (size_t)M * 2048 * 2;
    uint16_t* W0b = (uint16_t*)w; w += (size_t)2048 * 1024 * 2;
    uint16_t* W1b = (uint16_t*)w; w += (size_t)2048 * 2048 * 2;
    uint16_t* W2b = (uint16_t*)w; w += (size_t)64 * 2048 * 2;

    cvt8<<<M * 1024 / 8 / 256, 256, 0, stream>>>(X, X0, M * 1024);
    cvt8<<<2048 * 1024 / 8 / 256, 256, 0, stream>>>(W0, W0b, 2048 * 1024);
    cvt8<<<2048 * 2048 / 8 / 256, 256, 0, stream>>>(W1, W1b, 2048 * 2048);
    cvt_pad_w2<<<64 * 2048 / 8 / 256, 256, 0, stream>>>(W2, W2b);

    // layer 0: [16384,1024] x [2048,1024]^T -> relu -> bf16; 128x256 tiles
    gemm_bt<4, 8, true, false><<<dim3((M / 128) * (2048 / 256)), 256, 0, stream>>>(
        X0, W0b, b0, X1, M, 2048, 1024, 2048, 2048);
    // layer 1: [16384,2048] x [2048,2048]^T -> relu -> bf16; 128x256 tiles
    gemm_bt<4, 8, true, false><<<dim3((M / 128) * (2048 / 256)), 256, 0, stream>>>(
        X1, W1b, b1, X2, M, 2048, 2048, 2048, 2048);
    // layer 2: [16384,2048] x [64(pad 51),2048]^T -> fp32; 32x64 tiles, 512 blocks
    gemm_bt<1, 2, false, true><<<dim3(M / 32), 256, 0, stream>>>(
        X2, W2b, b2, d_out, M, 64, 2048, 51, 51);
}